// Round 11
// baseline (747.161 us; speedup 1.0000x reference)
//
#include <hip/hip_runtime.h>

#define NN 131072   // nodes
#define NG 4096     // graphs
#define NE 524288   // edges

__device__ __forceinline__ float lrelu(float a){ return a>=0.f ? a : 0.2f*a; }

// ============================================================================
// pool_gemm v9 (proven 83us): scalar-path W + 64 rows / 512-thread blocks.
//   Wave w (0..7) owns wave-uniform 16-col W slice (s_load -> SGPR).
//   Lane (0..63) = output row. accv[16]/thread. W/block = 64KB non-redundant.
//   xs pitch 132/44. LDS ~34KB -> 4 blocks/CU x 8 waves = 32 waves/CU.
//   Gate folded into store ((t*x)@W = t*(x@W)); readout applies tsS on the fly.
// ============================================================================
template<int K, int PMODE, int KSEL>
__global__ __launch_bounds__(512) void pool_gemm_kernel(
    const float* __restrict__ Xin, float* bufA, unsigned char* nmg,
    const float* __restrict__ stat,    // [0:128] mean, [128:256] rstd, [256:384] pw/||pw||
    const float* __restrict__ gamma, const float* __restrict__ beta,
    const float* __restrict__ Wg,      // K x 128
    float* zacc)
{
    constexpr int XP = (K == 41) ? 44 : 132;   // padded LDS pitch
    __shared__ float xs[64 * XP];
    __shared__ float scS[64], tsS[64];
    __shared__ int   nmlS[64];

    int tid = threadIdx.x;
    long row0 = (long)blockIdx.x * 64;
    int g0 = blockIdx.x * 2;

    if (PMODE == 0) {
        for (int i = tid; i < 64 * 41; i += 512) {
            int r = i / 41, c = i - r * 41;
            xs[r * 44 + c] = Xin[row0 * 41 + i];
        }
    } else {
        for (int i = tid; i < 2048; i += 512) {
            int r = i >> 5, dc = (i & 31) * 4;
            float4 v = *(const float4*)&bufA[(row0 + r) * 128 + dc];
            v.x = fmaxf(gamma[dc    ] * (v.x - stat[dc    ]) * stat[128 + dc    ] + beta[dc    ], 0.f);
            v.y = fmaxf(gamma[dc + 1] * (v.y - stat[dc + 1]) * stat[128 + dc + 1] + beta[dc + 1], 0.f);
            v.z = fmaxf(gamma[dc + 2] * (v.z - stat[dc + 2]) * stat[128 + dc + 2] + beta[dc + 2], 0.f);
            v.w = fmaxf(gamma[dc + 3] * (v.w - stat[dc + 3]) * stat[128 + dc + 3] + beta[dc + 3], 0.f);
            *(float4*)&xs[r * XP + dc] = v;
        }
        if (tid < 64) nmlS[tid] = (PMODE == 1) ? 1 : (int)nmg[g0 * 32 + tid];
    }
    __syncthreads();

    if (PMODE > 0) {
        {   // pool scores: 8 lanes/node over 64 nodes
            int node = tid >> 3, l8 = tid & 7;
            float s = 0.f;
#pragma unroll
            for (int m = 0; m < 16; m++) { int c = l8 + 8 * m; s += xs[node * XP + c] * stat[256 + c]; }
            s += __shfl_xor(s, 4); s += __shfl_xor(s, 2); s += __shfl_xor(s, 1);
            if (l8 == 0) scS[node] = s;
        }
        __syncthreads();
        if (tid < 64) {   // stable top-k (ties: lower index wins)
            int gp = tid >> 5, n = tid & 31;
            float sn = nmlS[tid] ? scS[tid] : -1e9f;
            int cnt = 0;
            for (int j = 0; j < 32; j++) {
                float sj = nmlS[gp * 32 + j] ? scS[gp * 32 + j] : -1e9f;
                cnt += (sj > sn || (sj == sn && j < n)) ? 1 : 0;
            }
            int sl = (cnt < KSEL) ? 1 : 0;
            nmg[g0 * 32 + tid] = (unsigned char)sl;
            tsS[tid] = sl ? tanhf(scS[tid]) : 0.f;
        }
        __syncthreads();
        if (tid < 256) {   // readout, gate applied on the fly (xs stays ungated)
            int gp = tid >> 7, d = tid & 127;
            float s = 0.f;
            for (int n = 0; n < 32; n++) s += tsS[gp * 32 + n] * xs[(gp * 32 + n) * XP + d];
            zacc[(long)(g0 + gp) * 128 + d] += s * (1.0f / (float)KSEL);
        }
        // no barrier: readout and GEMM both only READ xs/tsS
    }

    // ---- GEMM: lane = row (64); wave (0..7) = wave-uniform 16-col W slice
    int lane = tid & 63;
    int wv = __builtin_amdgcn_readfirstlane(tid >> 6);   // 0..7, uniform
    const float* __restrict__ Wb = Wg + wv * 16;

    float accv[16];
#pragma unroll
    for (int c = 0; c < 16; c++) accv[c] = 0.f;

    constexpr int KM4 = (K / 4) * 4;
#pragma unroll 2
    for (int k0 = 0; k0 < KM4; k0 += 4) {
        float4 xv = *(const float4*)&xs[lane * XP + k0];
        {
            const float* Wr = Wb + (k0 + 0) * 128;
#pragma unroll
            for (int c = 0; c < 16; c++) accv[c] += xv.x * Wr[c];
        }
        {
            const float* Wr = Wb + (k0 + 1) * 128;
#pragma unroll
            for (int c = 0; c < 16; c++) accv[c] += xv.y * Wr[c];
        }
        {
            const float* Wr = Wb + (k0 + 2) * 128;
#pragma unroll
            for (int c = 0; c < 16; c++) accv[c] += xv.z * Wr[c];
        }
        {
            const float* Wr = Wb + (k0 + 3) * 128;
#pragma unroll
            for (int c = 0; c < 16; c++) accv[c] += xv.w * Wr[c];
        }
    }
    for (int k = KM4; k < K; k++) {
        float xk = xs[lane * XP + k];
        const float* Wr = Wb + k * 128;
#pragma unroll
        for (int c = 0; c < 16; c++) accv[c] += xk * Wr[c];
    }

    // ---- store: thread covers bufA[row0+lane][wv*16 .. wv*16+15] (64B contig)
    {
        float t = 1.f;
        if (PMODE > 0) t = tsS[lane];
        float* orow = &bufA[(row0 + lane) * 128 + wv * 16];
#pragma unroll
        for (int cc = 0; cc < 4; cc++)
            *(float4*)&orow[cc * 4] = make_float4(
                accv[cc * 4 + 0] * t, accv[cc * 4 + 1] * t,
                accv[cc * 4 + 2] * t, accv[cc * 4 + 3] * t);
    }
}

// ============================================================================
// attn v11: v3 structure with re-tiled AGG (4n x 4d per thread).
//   Per s per thread: 1 ds_read_b128 hs + 1 ds_read_b128 Wm + 16 FMA
//   -> block LDS instrs in AGG 640 -> 256 (2.5x fewer).
//   hs b128: wave spans full 512B row -> 2-way (free). Wm b128: 4 distinct
//   addresses per wave -> broadcast.
// LDS 26912 B -> 6 blocks/CU.
// ============================================================================
__global__ __launch_bounds__(256) void attn_kernel(
    float* bufA,
    const int* __restrict__ srcp, const int* __restrict__ dstp,
    const float* __restrict__ EA,
    const unsigned char* __restrict__ nmg,
    const float* __restrict__ stat,      // ve at [384:404]
    const float* __restrict__ as_, const float* __restrict__ ad_,
    const float* __restrict__ bb,
    float* sums)                          // [32][256] replicated {sum[128], sq[128]}
{
    __shared__ float hs[32 * 128];       // 16 KB, XOR-swizzled 16B chunks
    __shared__ float Wm[2 * 32 * 36];    // 9216 B, [h][src s][dst n], pitch 36
    __shared__ float scr[320];           // [0:256]: P2/P3 hsd|hdd|lsum|lcnt, then BN red
                                         // [256:320]: rden
    __shared__ unsigned char nmlS[32];

    int g = blockIdx.x, tid = threadIdx.x;
    long gb = (long)g * 4096;

    // ---------------- P1: loads + zero + swizzled stage ----------------
    float ea0 = 0.f, ea1 = 0.f;
    int myls = 0, myld = 0;
    if (tid < 128) {
        myls = srcp[g * 128 + tid] & 31;
        myld = dstp[g * 128 + tid] & 31;
        const float* ep = EA + (long)(g * 128 + tid) * 10;
#pragma unroll
        for (int j = 0; j < 10; j++) { float v = ep[j]; ea0 += v * stat[384 + j]; ea1 += v * stat[394 + j]; }
    }
    for (int i = tid; i < 2304; i += 256) Wm[i] = 0.f;
    if (tid < 96) scr[128 + tid] = 0.f;          // zero lsum[128:192] + lcnt[192:224]
    if (tid < 32) nmlS[tid] = nmg[g * 32 + tid];
#pragma unroll
    for (int k = 0; k < 4; k++) {                 // global -> LDS, swizzled
        int i = tid + 256 * k, r = i >> 5, c4 = i & 31;
        *(float4*)&hs[r * 128 + ((c4 ^ (r & 7)) << 2)] =
            *(const float4*)&bufA[gb + (long)i * 4];
    }
    __syncthreads();   // bar1

    // ---------------- P2: node dots + loop-attr sums ----------------
    {
        int node = tid >> 3, l8 = tid & 7, rb = node * 128, k = node & 7;
        float s0 = 0, s1 = 0, d0 = 0, d1 = 0;
#pragma unroll
        for (int m = 0; m < 8; m++) {
            int c = l8 + 8 * m, c4 = c >> 2, j = c & 3;
            int o0 = rb + ((c4 ^ k) << 2) + j;
            float h0 = hs[o0], h1 = hs[o0 + 64];   // (c4+16)^k == (c4^k)+16
            s0 += h0 * as_[c];      s1 += h1 * as_[64 + c];
            d0 += h0 * ad_[c];      d1 += h1 * ad_[64 + c];
        }
        s0 += __shfl_xor(s0, 4); s0 += __shfl_xor(s0, 2); s0 += __shfl_xor(s0, 1);
        s1 += __shfl_xor(s1, 4); s1 += __shfl_xor(s1, 2); s1 += __shfl_xor(s1, 1);
        d0 += __shfl_xor(d0, 4); d0 += __shfl_xor(d0, 2); d0 += __shfl_xor(d0, 1);
        d1 += __shfl_xor(d1, 4); d1 += __shfl_xor(d1, 2); d1 += __shfl_xor(d1, 1);
        if (l8 == 0) {
            scr[node * 2] = s0;      scr[node * 2 + 1] = s1;       // hsd
            scr[64 + node * 2] = d0; scr[64 + node * 2 + 1] = d1;  // hdd
        }
    }
    int mymk = 0;
    if (tid < 128) {
        mymk = (int)nmlS[myls] & (int)nmlS[myld];
        if (mymk) {
            atomicAdd(&scr[128 + myld * 2], ea0);
            atomicAdd(&scr[128 + myld * 2 + 1], ea1);
            atomicAdd(&scr[192 + myld], 1.f);
        }
    }
    __syncthreads();   // bar2

    // ---------------- P3: exp(alpha) scatter into Wm ----------------
    if (tid < 128) {
        if (mymk) {
            float p0 = __expf(lrelu(scr[myls * 2]     + scr[64 + myld * 2]     + ea0));
            float p1 = __expf(lrelu(scr[myls * 2 + 1] + scr[64 + myld * 2 + 1] + ea1));
            atomicAdd(&Wm[myls * 36 + myld], p0);
            atomicAdd(&Wm[1152 + myls * 36 + myld], p1);
        }
    } else if (tid < 192) {
        int t2 = tid - 128, n = t2 >> 1, h = t2 & 1;
        if (nmlS[n]) {
            float c = scr[192 + n]; c = (c > 0.f) ? c : 1.f;
            float ps = __expf(lrelu(scr[n * 2 + h] + scr[64 + n * 2 + h] + scr[128 + n * 2 + h] / c));
            atomicAdd(&Wm[h * 1152 + n * 36 + n], ps);
        }
    }
    __syncthreads();   // bar3

    // ---------------- B4: den = column sums of Wm (1 wave) + zero BN red ----
    if (tid < 64) {
        int n = tid & 31, h = tid >> 5;
        const float* Wh = &Wm[h * 1152 + n];
        float den = 0.f;
#pragma unroll 8
        for (int s = 0; s < 32; s++) den += Wh[s * 36];
        scr[256 + h * 32 + n] = 1.f / fmaxf(den, 1e-16f);
    } else if (tid < 128) {
        *(float4*)&scr[(tid - 64) * 4] = make_float4(0.f, 0.f, 0.f, 0.f);
    }
    __syncthreads();   // bar4

    // ---------------- AGG v2: 4n x 4d tile per thread ----------------
    // thread: d4 = tid&31 (d = d4*4+j), h = d4>>4, n4 = tid>>5 (n = n4*4+i)
    {
        int d4 = tid & 31, h = d4 >> 4, n4 = tid >> 5;
        const float* Wh = &Wm[h * 1152 + n4 * 4];
        float4 a0 = make_float4(0,0,0,0), a1 = a0, a2 = a0, a3 = a0;
        for (int s = 0; s < 32; s++) {
            float4 hv = *(const float4*)&hs[s * 128 + ((d4 ^ (s & 7)) << 2)];
            float4 wv = *(const float4*)&Wh[s * 36];
            a0.x += wv.x * hv.x; a0.y += wv.x * hv.y; a0.z += wv.x * hv.z; a0.w += wv.x * hv.w;
            a1.x += wv.y * hv.x; a1.y += wv.y * hv.y; a1.z += wv.y * hv.z; a1.w += wv.y * hv.w;
            a2.x += wv.z * hv.x; a2.y += wv.z * hv.y; a2.z += wv.z * hv.z; a2.w += wv.z * hv.w;
            a3.x += wv.w * hv.x; a3.y += wv.w * hv.y; a3.z += wv.w * hv.z; a3.w += wv.w * hv.w;
        }
        float4 bv = *(const float4*)&bb[d4 * 4];
        float4 sp = make_float4(0,0,0,0), sq = sp;
        float* ob = &bufA[gb + (long)(n4 * 4) * 128 + d4 * 4];
#define AGG_ROW(I, ACC)                                                        \
        {                                                                      \
            int n = n4 * 4 + (I);                                              \
            float r = scr[256 + h * 32 + n];                                   \
            float4 v;                                                          \
            v.x = ACC.x * r + bv.x; v.y = ACC.y * r + bv.y;                    \
            v.z = ACC.z * r + bv.z; v.w = ACC.w * r + bv.w;                    \
            *(float4*)&ob[(I) * 128] = v;                                      \
            if (nmlS[n]) {                                                     \
                sp.x += v.x; sp.y += v.y; sp.z += v.z; sp.w += v.w;            \
                sq.x += v.x * v.x; sq.y += v.y * v.y;                          \
                sq.z += v.z * v.z; sq.w += v.w * v.w;                          \
            }                                                                  \
        }
        AGG_ROW(0, a0)
        AGG_ROW(1, a1)
        AGG_ROW(2, a2)
        AGG_ROW(3, a3)
#undef AGG_ROW
        int db = d4 * 4;
        atomicAdd(&scr[db    ], sp.x); atomicAdd(&scr[db + 1], sp.y);
        atomicAdd(&scr[db + 2], sp.z); atomicAdd(&scr[db + 3], sp.w);
        atomicAdd(&scr[128 + db    ], sq.x); atomicAdd(&scr[128 + db + 1], sq.y);
        atomicAdd(&scr[128 + db + 2], sq.z); atomicAdd(&scr[128 + db + 3], sq.w);
    }
    __syncthreads();   // bar5

    if (tid < 128) {
        int rep = (g & 31) * 256;
        atomicAdd(&sums[rep + tid], scr[tid]);
        atomicAdd(&sums[rep + 128 + tid], scr[128 + tid]);
    }
}

// ============================================================================
__global__ __launch_bounds__(128) void setup_kernel(
    float* sums, float* stat, const float* __restrict__ We, const float* __restrict__ ae)
{
    int t = threadIdx.x;
    for (int i = t; i < 32 * 256; i += 128) sums[i] = 0.f;
    if (t < 20) {
        int h = t / 10, j = t - 10 * h;
        float s = 0.f;
        for (int c = 0; c < 64; c++) s += We[j * 128 + h * 64 + c] * ae[h * 64 + c];
        stat[384 + t] = s;
    }
}

__global__ __launch_bounds__(128) void finalize_kernel(
    float* sums, float n, const float* __restrict__ pw, float* stat,
    const float* __restrict__ Wen, const float* __restrict__ aen)
{
    int d = threadIdx.x;
    float s1 = 0.f, s2 = 0.f;
#pragma unroll
    for (int r = 0; r < 32; r++) { s1 += sums[r * 256 + d]; s2 += sums[r * 256 + 128 + d]; }
    float mean = s1 / n;
    float var = s2 / n - mean * mean;
    if (var < 0.f) var = 0.f;
    float rstd = rsqrtf(var + 1e-5f);
    float p = pw[d];
    float q = p * p;
#pragma unroll
    for (int o = 32; o >= 1; o >>= 1) q += __shfl_xor(q, o);
    __shared__ float w2[2];
    if ((d & 63) == 0) w2[d >> 6] = q;
    __syncthreads();
    float nrm = sqrtf(w2[0] + w2[1]);
    stat[d] = mean; stat[128 + d] = rstd; stat[256 + d] = p / nrm;
    if (d < 20) {
        int h = d / 10, j = d - 10 * h;
        float s = 0.f;
        for (int c = 0; c < 64; c++) s += Wen[j * 128 + h * 64 + c] * aen[h * 64 + c];
        stat[384 + d] = s;
    }
    for (int i = d; i < 32 * 256; i += 128) sums[i] = 0.f;
}

// ============================================================================
// final: pool layer-2 output (K=25) + readout + MLP head
// ============================================================================
__global__ __launch_bounds__(256) void final_kernel(
    const float* __restrict__ bufA, const unsigned char* __restrict__ nmg,
    const float* __restrict__ stat,
    const float* __restrict__ gamma, const float* __restrict__ beta,
    const float* __restrict__ zacc,
    const float* __restrict__ fw1, const float* __restrict__ fb1,
    const float* __restrict__ fw2, const float* __restrict__ fb2,
    float* __restrict__ out)
{
    __shared__ float xs[32 * 132], zt[128], hred[64], scS[32], tsS[32];
    __shared__ int nmlS[32];
    int g = blockIdx.x, tid = threadIdx.x;
    long gb = (long)g * 4096;

    if (tid < 32) nmlS[tid] = (int)nmg[g * 32 + tid];
    for (int i = tid; i < 1024; i += 256) {
        int r = i >> 5, dc = (i & 31) * 4;
        float4 v = *(const float4*)&bufA[gb + i * 4];
        v.x = fmaxf(gamma[dc    ] * (v.x - stat[dc    ]) * stat[128 + dc    ] + beta[dc    ], 0.f);
        v.y = fmaxf(gamma[dc + 1] * (v.y - stat[dc + 1]) * stat[128 + dc + 1] + beta[dc + 1], 0.f);
        v.z = fmaxf(gamma[dc + 2] * (v.z - stat[dc + 2]) * stat[128 + dc + 2] + beta[dc + 2], 0.f);
        v.w = fmaxf(gamma[dc + 3] * (v.w - stat[dc + 3]) * stat[128 + dc + 3] + beta[dc + 3], 0.f);
        *(float4*)&xs[r * 132 + dc] = v;
    }
    __syncthreads();

    {
        int node = tid >> 3, l8 = tid & 7;
        float s = 0.f;
        for (int m = 0; m < 16; m++) { int c = l8 + 8 * m; s += xs[node * 132 + c] * stat[256 + c]; }
        s += __shfl_xor(s, 4); s += __shfl_xor(s, 2); s += __shfl_xor(s, 1);
        if (l8 == 0) scS[node] = s;
    }
    __syncthreads();

    if (tid < 32) {
        float sn = nmlS[tid] ? scS[tid] : -1e9f;
        int cnt = 0;
        for (int j = 0; j < 32; j++) {
            float sj = nmlS[j] ? scS[j] : -1e9f;
            cnt += (sj > sn || (sj == sn && j < tid)) ? 1 : 0;
        }
        tsS[tid] = (cnt < 25) ? tanhf(scS[tid]) : 0.f;
    }
    __syncthreads();

    if (tid < 128) {
        float s = 0.f;
        for (int n = 0; n < 32; n++) s += xs[n * 132 + tid] * tsS[n];
        zt[tid] = zacc[(long)g * 128 + tid] + s * (1.0f / 25.0f);
    }
    __syncthreads();

    {
        int j = tid >> 2, p = tid & 3;
        float s = 0.f;
        for (int d = p * 32; d < p * 32 + 32; d++) s += zt[d] * fw1[d * 64 + j];
        s += __shfl_xor(s, 1); s += __shfl_xor(s, 2);
        if (p == 0) hred[j] = fmaxf(s + fb1[j], 0.f) * fw2[j];
    }
    __syncthreads();
    if (tid < 64) {
        float v = hred[tid];
#pragma unroll
        for (int o = 32; o >= 1; o >>= 1) v += __shfl_xor(v, o);
        if (tid == 0) out[g] = v + fb2[0];
    }
}

extern "C" void kernel_launch(void* const* d_in, const int* in_sizes, int n_in,
                              void* d_out, int out_size, void* d_ws, size_t ws_size,
                              hipStream_t stream)
{
    const float* X0 = (const float*)d_in[0];
    const int*   EI = (const int*)d_in[1];
    const float* EA = (const float*)d_in[2];
    const int* srcp = EI;
    const int* dstp = EI + NE;

    const float* W1  = (const float*)d_in[4];  const float* We1 = (const float*)d_in[5];
    const float* as1 = (const float*)d_in[6];  const float* ad1 = (const float*)d_in[7];
    const float* ae1 = (const float*)d_in[8];  const float* b1  = (const float*)d_in[9];
    const float* g1  = (const float*)d_in[10]; const float* be1 = (const float*)d_in[11];
    const float* pw1 = (const float*)d_in[12];
    const float* W2  = (const float*)d_in[13]; const float* We2 = (const float*)d_in[14];
    const float* as2 = (const float*)d_in[15]; const float* ad2 = (const float*)d_in[16];
    const float* ae2 = (const float*)d_in[17]; const float* b2  = (const float*)d_in[18];
    const float* g2  = (const float*)d_in[19]; const float* be2 = (const float*)d_in[20];
    const float* pw2 = (const float*)d_in[21];
    const float* W3  = (const float*)d_in[22]; const float* We3 = (const float*)d_in[23];
    const float* as3 = (const float*)d_in[24]; const float* ad3 = (const float*)d_in[25];
    const float* ae3 = (const float*)d_in[26]; const float* b3  = (const float*)d_in[27];
    const float* g3  = (const float*)d_in[28]; const float* be3 = (const float*)d_in[29];
    const float* pw3 = (const float*)d_in[30];
    const float* fw1 = (const float*)d_in[31]; const float* fb1 = (const float*)d_in[32];
    const float* fw2 = (const float*)d_in[33]; const float* fb2 = (const float*)d_in[34];

    float* bufA = (float*)d_ws;                       // NN*128 f32
    float* z    = bufA + (size_t)NN * 128;            // NG*128 f32
    float* sums = z + (size_t)NG * 128;               // 32*256 f32 (replicated)
    float* stat = sums + 32 * 256;                    // 512 f32
    unsigned char* nmg = (unsigned char*)(stat + 512);// NG*32 bytes

    hipMemsetAsync(nmg, 1, NN, stream);
    hipMemsetAsync(z, 0, (size_t)NG * 128 * sizeof(float), stream);
    setup_kernel<<<1, 128, 0, stream>>>(sums, stat, We1, ae1);

    // layer 0
    pool_gemm_kernel<41, 0, 1><<<NN / 64, 512, 0, stream>>>(
        X0, bufA, nmg, stat, g1, be1, W1, z);
    attn_kernel<<<NG, 256, 0, stream>>>(bufA, srcp, dstp, EA, nmg, stat, as1, ad1, b1, sums);
    finalize_kernel<<<1, 128, 0, stream>>>(sums, 131072.f, pw1, stat, We2, ae2);

    // layer 1 (pools layer-0 output, K=29)
    pool_gemm_kernel<128, 1, 29><<<NN / 64, 512, 0, stream>>>(
        X0, bufA, nmg, stat, g1, be1, W2, z);
    attn_kernel<<<NG, 256, 0, stream>>>(bufA, srcp, dstp, EA, nmg, stat, as2, ad2, b2, sums);
    finalize_kernel<<<1, 128, 0, stream>>>(sums, 4096.f * 29.f, pw2, stat, We3, ae3);

    // layer 2 (pools layer-1 output, K=27)
    pool_gemm_kernel<128, 2, 27><<<NN / 64, 512, 0, stream>>>(
        X0, bufA, nmg, stat, g2, be2, W3, z);
    attn_kernel<<<NG, 256, 0, stream>>>(bufA, srcp, dstp, EA, nmg, stat, as3, ad3, b3, sums);
    finalize_kernel<<<1, 128, 0, stream>>>(sums, 4096.f * 27.f, pw3, stat, We3, ae3);

    // final: pool layer-2 output (K=25) + readout + head
    final_kernel<<<NG, 256, 0, stream>>>(
        bufA, nmg, stat, g3, be3, z, fw1, fb1, fw2, fb2, (float*)d_out);
}

// Round 12
// 511.215 us; speedup vs baseline: 1.4615x; 1.4615x over previous
//
#include <hip/hip_runtime.h>

#define NN 131072   // nodes
#define NG 4096     // graphs
#define NE 524288   // edges

__device__ __forceinline__ float lrelu(float a){ return a>=0.f ? a : 0.2f*a; }

// ============================================================================
// pool_gemm v9 (proven 83us): scalar-path W + 64 rows / 512-thread blocks.
//   Wave w (0..7) owns wave-uniform 16-col W slice (s_load -> SGPR).
//   Lane (0..63) = output row. accv[16]/thread. W/block = 64KB non-redundant.
//   xs pitch 132/44. LDS ~34KB -> 4 blocks/CU x 8 waves = 32 waves/CU.
//   Gate folded into store ((t*x)@W = t*(x@W)); readout applies tsS on the fly.
// ============================================================================
template<int K, int PMODE, int KSEL>
__global__ __launch_bounds__(512) void pool_gemm_kernel(
    const float* __restrict__ Xin, float* bufA, unsigned char* nmg,
    const float* __restrict__ stat,    // [0:128] mean, [128:256] rstd, [256:384] pw/||pw||
    const float* __restrict__ gamma, const float* __restrict__ beta,
    const float* __restrict__ Wg,      // K x 128
    float* zacc)
{
    constexpr int XP = (K == 41) ? 44 : 132;   // padded LDS pitch
    __shared__ float xs[64 * XP];
    __shared__ float scS[64], tsS[64];
    __shared__ int   nmlS[64];

    int tid = threadIdx.x;
    long row0 = (long)blockIdx.x * 64;
    int g0 = blockIdx.x * 2;

    if (PMODE == 0) {
        for (int i = tid; i < 64 * 41; i += 512) {
            int r = i / 41, c = i - r * 41;
            xs[r * 44 + c] = Xin[row0 * 41 + i];
        }
    } else {
        for (int i = tid; i < 2048; i += 512) {
            int r = i >> 5, dc = (i & 31) * 4;
            float4 v = *(const float4*)&bufA[(row0 + r) * 128 + dc];
            v.x = fmaxf(gamma[dc    ] * (v.x - stat[dc    ]) * stat[128 + dc    ] + beta[dc    ], 0.f);
            v.y = fmaxf(gamma[dc + 1] * (v.y - stat[dc + 1]) * stat[128 + dc + 1] + beta[dc + 1], 0.f);
            v.z = fmaxf(gamma[dc + 2] * (v.z - stat[dc + 2]) * stat[128 + dc + 2] + beta[dc + 2], 0.f);
            v.w = fmaxf(gamma[dc + 3] * (v.w - stat[dc + 3]) * stat[128 + dc + 3] + beta[dc + 3], 0.f);
            *(float4*)&xs[r * XP + dc] = v;
        }
        if (tid < 64) nmlS[tid] = (PMODE == 1) ? 1 : (int)nmg[g0 * 32 + tid];
    }
    __syncthreads();

    if (PMODE > 0) {
        {   // pool scores: 8 lanes/node over 64 nodes
            int node = tid >> 3, l8 = tid & 7;
            float s = 0.f;
#pragma unroll
            for (int m = 0; m < 16; m++) { int c = l8 + 8 * m; s += xs[node * XP + c] * stat[256 + c]; }
            s += __shfl_xor(s, 4); s += __shfl_xor(s, 2); s += __shfl_xor(s, 1);
            if (l8 == 0) scS[node] = s;
        }
        __syncthreads();
        if (tid < 64) {   // stable top-k (ties: lower index wins)
            int gp = tid >> 5, n = tid & 31;
            float sn = nmlS[tid] ? scS[tid] : -1e9f;
            int cnt = 0;
            for (int j = 0; j < 32; j++) {
                float sj = nmlS[gp * 32 + j] ? scS[gp * 32 + j] : -1e9f;
                cnt += (sj > sn || (sj == sn && j < n)) ? 1 : 0;
            }
            int sl = (cnt < KSEL) ? 1 : 0;
            nmg[g0 * 32 + tid] = (unsigned char)sl;
            tsS[tid] = sl ? tanhf(scS[tid]) : 0.f;
        }
        __syncthreads();
        if (tid < 256) {   // readout, gate applied on the fly (xs stays ungated)
            int gp = tid >> 7, d = tid & 127;
            float s = 0.f;
            for (int n = 0; n < 32; n++) s += tsS[gp * 32 + n] * xs[(gp * 32 + n) * XP + d];
            zacc[(long)(g0 + gp) * 128 + d] += s * (1.0f / (float)KSEL);
        }
        // no barrier: readout and GEMM both only READ xs/tsS
    }

    // ---- GEMM: lane = row (64); wave (0..7) = wave-uniform 16-col W slice
    int lane = tid & 63;
    int wv = __builtin_amdgcn_readfirstlane(tid >> 6);   // 0..7, uniform
    const float* __restrict__ Wb = Wg + wv * 16;

    float accv[16];
#pragma unroll
    for (int c = 0; c < 16; c++) accv[c] = 0.f;

    constexpr int KM4 = (K / 4) * 4;
#pragma unroll 2
    for (int k0 = 0; k0 < KM4; k0 += 4) {
        float4 xv = *(const float4*)&xs[lane * XP + k0];
        {
            const float* Wr = Wb + (k0 + 0) * 128;
#pragma unroll
            for (int c = 0; c < 16; c++) accv[c] += xv.x * Wr[c];
        }
        {
            const float* Wr = Wb + (k0 + 1) * 128;
#pragma unroll
            for (int c = 0; c < 16; c++) accv[c] += xv.y * Wr[c];
        }
        {
            const float* Wr = Wb + (k0 + 2) * 128;
#pragma unroll
            for (int c = 0; c < 16; c++) accv[c] += xv.z * Wr[c];
        }
        {
            const float* Wr = Wb + (k0 + 3) * 128;
#pragma unroll
            for (int c = 0; c < 16; c++) accv[c] += xv.w * Wr[c];
        }
    }
    for (int k = KM4; k < K; k++) {
        float xk = xs[lane * XP + k];
        const float* Wr = Wb + k * 128;
#pragma unroll
        for (int c = 0; c < 16; c++) accv[c] += xk * Wr[c];
    }

    // ---- store: thread covers bufA[row0+lane][wv*16 .. wv*16+15] (64B contig)
    {
        float t = 1.f;
        if (PMODE > 0) t = tsS[lane];
        float* orow = &bufA[(row0 + lane) * 128 + wv * 16];
#pragma unroll
        for (int cc = 0; cc < 4; cc++)
            *(float4*)&orow[cc * 4] = make_float4(
                accv[cc * 4 + 0] * t, accv[cc * 4 + 1] * t,
                accv[cc * 4 + 2] * t, accv[cc * 4 + 3] * t);
    }
}

// ============================================================================
// attn v3 (proven): wave-uniform Wm reads, acc[16] agg, B4 den phase,
// hs pitch 128 XOR-swizzled, 32-way replicated global BN sums.
// LDS 26912 B -> 6 blocks/CU. DO NOT re-tile AGG: 4x4 register tiles
// (v2/v11) blow VGPR to 144-188 and occupancy to 11% — failed twice.
// ============================================================================
__global__ __launch_bounds__(256) void attn_kernel(
    float* bufA,
    const int* __restrict__ srcp, const int* __restrict__ dstp,
    const float* __restrict__ EA,
    const unsigned char* __restrict__ nmg,
    const float* __restrict__ stat,      // ve at [384:404]
    const float* __restrict__ as_, const float* __restrict__ ad_,
    const float* __restrict__ bb,
    float* sums)                          // [32][256] replicated {sum[128], sq[128]}
{
    __shared__ float hs[32 * 128];       // 16 KB, XOR-swizzled 16B chunks
    __shared__ float Wm[2 * 32 * 36];    // 9216 B, [h][src s][dst n], pitch 36
    __shared__ float scr[320];           // [0:256]: P2/P3 hsd|hdd|lsum|lcnt, then BN red
                                         // [256:320]: rden
    __shared__ unsigned char nmlS[32];

    int g = blockIdx.x, tid = threadIdx.x;
    long gb = (long)g * 4096;

    // ---------------- P1: loads + zero + swizzled stage ----------------
    float ea0 = 0.f, ea1 = 0.f;
    int myls = 0, myld = 0;
    if (tid < 128) {
        myls = srcp[g * 128 + tid] & 31;
        myld = dstp[g * 128 + tid] & 31;
        const float* ep = EA + (long)(g * 128 + tid) * 10;
#pragma unroll
        for (int j = 0; j < 10; j++) { float v = ep[j]; ea0 += v * stat[384 + j]; ea1 += v * stat[394 + j]; }
    }
    for (int i = tid; i < 2304; i += 256) Wm[i] = 0.f;
    if (tid < 96) scr[128 + tid] = 0.f;          // zero lsum[128:192] + lcnt[192:224]
    if (tid < 32) nmlS[tid] = nmg[g * 32 + tid];
#pragma unroll
    for (int k = 0; k < 4; k++) {                 // global -> LDS, swizzled
        int i = tid + 256 * k, r = i >> 5, c4 = i & 31;
        *(float4*)&hs[r * 128 + ((c4 ^ (r & 7)) << 2)] =
            *(const float4*)&bufA[gb + (long)i * 4];
    }
    __syncthreads();   // bar1

    // ---------------- P2: node dots + loop-attr sums ----------------
    {
        int node = tid >> 3, l8 = tid & 7, rb = node * 128, k = node & 7;
        float s0 = 0, s1 = 0, d0 = 0, d1 = 0;
#pragma unroll
        for (int m = 0; m < 8; m++) {
            int c = l8 + 8 * m, c4 = c >> 2, j = c & 3;
            int o0 = rb + ((c4 ^ k) << 2) + j;
            float h0 = hs[o0], h1 = hs[o0 + 64];   // (c4+16)^k == (c4^k)+16
            s0 += h0 * as_[c];      s1 += h1 * as_[64 + c];
            d0 += h0 * ad_[c];      d1 += h1 * ad_[64 + c];
        }
        s0 += __shfl_xor(s0, 4); s0 += __shfl_xor(s0, 2); s0 += __shfl_xor(s0, 1);
        s1 += __shfl_xor(s1, 4); s1 += __shfl_xor(s1, 2); s1 += __shfl_xor(s1, 1);
        d0 += __shfl_xor(d0, 4); d0 += __shfl_xor(d0, 2); d0 += __shfl_xor(d0, 1);
        d1 += __shfl_xor(d1, 4); d1 += __shfl_xor(d1, 2); d1 += __shfl_xor(d1, 1);
        if (l8 == 0) {
            scr[node * 2] = s0;      scr[node * 2 + 1] = s1;       // hsd
            scr[64 + node * 2] = d0; scr[64 + node * 2 + 1] = d1;  // hdd
        }
    }
    int mymk = 0;
    if (tid < 128) {
        mymk = (int)nmlS[myls] & (int)nmlS[myld];
        if (mymk) {
            atomicAdd(&scr[128 + myld * 2], ea0);
            atomicAdd(&scr[128 + myld * 2 + 1], ea1);
            atomicAdd(&scr[192 + myld], 1.f);
        }
    }
    __syncthreads();   // bar2

    // ---------------- P3: exp(alpha) scatter into Wm ----------------
    if (tid < 128) {
        if (mymk) {
            float p0 = __expf(lrelu(scr[myls * 2]     + scr[64 + myld * 2]     + ea0));
            float p1 = __expf(lrelu(scr[myls * 2 + 1] + scr[64 + myld * 2 + 1] + ea1));
            atomicAdd(&Wm[myls * 36 + myld], p0);
            atomicAdd(&Wm[1152 + myls * 36 + myld], p1);
        }
    } else if (tid < 192) {
        int t2 = tid - 128, n = t2 >> 1, h = t2 & 1;
        if (nmlS[n]) {
            float c = scr[192 + n]; c = (c > 0.f) ? c : 1.f;
            float ps = __expf(lrelu(scr[n * 2 + h] + scr[64 + n * 2 + h] + scr[128 + n * 2 + h] / c));
            atomicAdd(&Wm[h * 1152 + n * 36 + n], ps);
        }
    }
    __syncthreads();   // bar3

    // ---------------- B4: den = column sums of Wm (1 wave) + zero BN red ----
    if (tid < 64) {
        int n = tid & 31, h = tid >> 5;
        const float* Wh = &Wm[h * 1152 + n];
        float den = 0.f;
#pragma unroll 8
        for (int s = 0; s < 32; s++) den += Wh[s * 36];
        scr[256 + h * 32 + n] = 1.f / fmaxf(den, 1e-16f);
    } else if (tid < 128) {
        *(float4*)&scr[(tid - 64) * 4] = make_float4(0.f, 0.f, 0.f, 0.f);
    }
    __syncthreads();   // bar4

    // ---------------- AGG: O[n,d] = rden[n] * sum_s Wm[s,n]*hs[s,d] + b[d] ----
    {
        int d = tid & 127, h = d >> 6, nb = tid >> 7;   // n = nb*16 + i
        int c4 = d >> 2, j = d & 3;
        const float* Wh = &Wm[h * 1152 + nb * 16];
        float acc[16];
#pragma unroll
        for (int i = 0; i < 16; i++) acc[i] = 0.f;
        for (int s = 0; s < 32; s++) {
            float hv = hs[s * 128 + ((c4 ^ (s & 7)) << 2) + j];
            float4 w0 = *(const float4*)&Wh[s * 36];
            float4 w1 = *(const float4*)&Wh[s * 36 + 4];
            float4 w2 = *(const float4*)&Wh[s * 36 + 8];
            float4 w3 = *(const float4*)&Wh[s * 36 + 12];
            acc[0]  += w0.x * hv; acc[1]  += w0.y * hv; acc[2]  += w0.z * hv; acc[3]  += w0.w * hv;
            acc[4]  += w1.x * hv; acc[5]  += w1.y * hv; acc[6]  += w1.z * hv; acc[7]  += w1.w * hv;
            acc[8]  += w2.x * hv; acc[9]  += w2.y * hv; acc[10] += w2.z * hv; acc[11] += w2.w * hv;
            acc[12] += w3.x * hv; acc[13] += w3.y * hv; acc[14] += w3.z * hv; acc[15] += w3.w * hv;
        }
        float bv = bb[d];
        float sp = 0.f, sq = 0.f;
#pragma unroll
        for (int i = 0; i < 16; i++) {
            int n = nb * 16 + i;
            float v = acc[i] * scr[256 + h * 32 + n] + bv;
            bufA[gb + n * 128 + d] = v;
            if (nmlS[n]) { sp += v; sq += v * v; }
        }
        atomicAdd(&scr[d], sp);
        atomicAdd(&scr[128 + d], sq);
    }
    __syncthreads();   // bar5

    if (tid < 128) {
        int rep = (g & 31) * 256;
        atomicAdd(&sums[rep + tid], scr[tid]);
        atomicAdd(&sums[rep + 128 + tid], scr[128 + tid]);
    }
}

// ============================================================================
__global__ __launch_bounds__(128) void setup_kernel(
    float* sums, float* stat, const float* __restrict__ We, const float* __restrict__ ae)
{
    int t = threadIdx.x;
    for (int i = t; i < 32 * 256; i += 128) sums[i] = 0.f;
    if (t < 20) {
        int h = t / 10, j = t - 10 * h;
        float s = 0.f;
        for (int c = 0; c < 64; c++) s += We[j * 128 + h * 64 + c] * ae[h * 64 + c];
        stat[384 + t] = s;
    }
}

__global__ __launch_bounds__(128) void finalize_kernel(
    float* sums, float n, const float* __restrict__ pw, float* stat,
    const float* __restrict__ Wen, const float* __restrict__ aen)
{
    int d = threadIdx.x;
    float s1 = 0.f, s2 = 0.f;
#pragma unroll
    for (int r = 0; r < 32; r++) { s1 += sums[r * 256 + d]; s2 += sums[r * 256 + 128 + d]; }
    float mean = s1 / n;
    float var = s2 / n - mean * mean;
    if (var < 0.f) var = 0.f;
    float rstd = rsqrtf(var + 1e-5f);
    float p = pw[d];
    float q = p * p;
#pragma unroll
    for (int o = 32; o >= 1; o >>= 1) q += __shfl_xor(q, o);
    __shared__ float w2[2];
    if ((d & 63) == 0) w2[d >> 6] = q;
    __syncthreads();
    float nrm = sqrtf(w2[0] + w2[1]);
    stat[d] = mean; stat[128 + d] = rstd; stat[256 + d] = p / nrm;
    if (d < 20) {
        int h = d / 10, j = d - 10 * h;
        float s = 0.f;
        for (int c = 0; c < 64; c++) s += Wen[j * 128 + h * 64 + c] * aen[h * 64 + c];
        stat[384 + d] = s;
    }
    for (int i = d; i < 32 * 256; i += 128) sums[i] = 0.f;
}

// ============================================================================
// final: pool layer-2 output (K=25) + readout + MLP head
// ============================================================================
__global__ __launch_bounds__(256) void final_kernel(
    const float* __restrict__ bufA, const unsigned char* __restrict__ nmg,
    const float* __restrict__ stat,
    const float* __restrict__ gamma, const float* __restrict__ beta,
    const float* __restrict__ zacc,
    const float* __restrict__ fw1, const float* __restrict__ fb1,
    const float* __restrict__ fw2, const float* __restrict__ fb2,
    float* __restrict__ out)
{
    __shared__ float xs[32 * 132], zt[128], hred[64], scS[32], tsS[32];
    __shared__ int nmlS[32];
    int g = blockIdx.x, tid = threadIdx.x;
    long gb = (long)g * 4096;

    if (tid < 32) nmlS[tid] = (int)nmg[g * 32 + tid];
    for (int i = tid; i < 1024; i += 256) {
        int r = i >> 5, dc = (i & 31) * 4;
        float4 v = *(const float4*)&bufA[gb + i * 4];
        v.x = fmaxf(gamma[dc    ] * (v.x - stat[dc    ]) * stat[128 + dc    ] + beta[dc    ], 0.f);
        v.y = fmaxf(gamma[dc + 1] * (v.y - stat[dc + 1]) * stat[128 + dc + 1] + beta[dc + 1], 0.f);
        v.z = fmaxf(gamma[dc + 2] * (v.z - stat[dc + 2]) * stat[128 + dc + 2] + beta[dc + 2], 0.f);
        v.w = fmaxf(gamma[dc + 3] * (v.w - stat[dc + 3]) * stat[128 + dc + 3] + beta[dc + 3], 0.f);
        *(float4*)&xs[r * 132 + dc] = v;
    }
    __syncthreads();

    {
        int node = tid >> 3, l8 = tid & 7;
        float s = 0.f;
        for (int m = 0; m < 16; m++) { int c = l8 + 8 * m; s += xs[node * 132 + c] * stat[256 + c]; }
        s += __shfl_xor(s, 4); s += __shfl_xor(s, 2); s += __shfl_xor(s, 1);
        if (l8 == 0) scS[node] = s;
    }
    __syncthreads();

    if (tid < 32) {
        float sn = nmlS[tid] ? scS[tid] : -1e9f;
        int cnt = 0;
        for (int j = 0; j < 32; j++) {
            float sj = nmlS[j] ? scS[j] : -1e9f;
            cnt += (sj > sn || (sj == sn && j < tid)) ? 1 : 0;
        }
        tsS[tid] = (cnt < 25) ? tanhf(scS[tid]) : 0.f;
    }
    __syncthreads();

    if (tid < 128) {
        float s = 0.f;
        for (int n = 0; n < 32; n++) s += xs[n * 132 + tid] * tsS[n];
        zt[tid] = zacc[(long)g * 128 + tid] + s * (1.0f / 25.0f);
    }
    __syncthreads();

    {
        int j = tid >> 2, p = tid & 3;
        float s = 0.f;
        for (int d = p * 32; d < p * 32 + 32; d++) s += zt[d] * fw1[d * 64 + j];
        s += __shfl_xor(s, 1); s += __shfl_xor(s, 2);
        if (p == 0) hred[j] = fmaxf(s + fb1[j], 0.f) * fw2[j];
    }
    __syncthreads();
    if (tid < 64) {
        float v = hred[tid];
#pragma unroll
        for (int o = 32; o >= 1; o >>= 1) v += __shfl_xor(v, o);
        if (tid == 0) out[g] = v + fb2[0];
    }
}

extern "C" void kernel_launch(void* const* d_in, const int* in_sizes, int n_in,
                              void* d_out, int out_size, void* d_ws, size_t ws_size,
                              hipStream_t stream)
{
    const float* X0 = (const float*)d_in[0];
    const int*   EI = (const int*)d_in[1];
    const float* EA = (const float*)d_in[2];
    const int* srcp = EI;
    const int* dstp = EI + NE;

    const float* W1  = (const float*)d_in[4];  const float* We1 = (const float*)d_in[5];
    const float* as1 = (const float*)d_in[6];  const float* ad1 = (const float*)d_in[7];
    const float* ae1 = (const float*)d_in[8];  const float* b1  = (const float*)d_in[9];
    const float* g1  = (const float*)d_in[10]; const float* be1 = (const float*)d_in[11];
    const float* pw1 = (const float*)d_in[12];
    const float* W2  = (const float*)d_in[13]; const float* We2 = (const float*)d_in[14];
    const float* as2 = (const float*)d_in[15]; const float* ad2 = (const float*)d_in[16];
    const float* ae2 = (const float*)d_in[17]; const float* b2  = (const float*)d_in[18];
    const float* g2  = (const float*)d_in[19]; const float* be2 = (const float*)d_in[20];
    const float* pw2 = (const float*)d_in[21];
    const float* W3  = (const float*)d_in[22]; const float* We3 = (const float*)d_in[23];
    const float* as3 = (const float*)d_in[24]; const float* ad3 = (const float*)d_in[25];
    const float* ae3 = (const float*)d_in[26]; const float* b3  = (const float*)d_in[27];
    const float* g3  = (const float*)d_in[28]; const float* be3 = (const float*)d_in[29];
    const float* pw3 = (const float*)d_in[30];
    const float* fw1 = (const float*)d_in[31]; const float* fb1 = (const float*)d_in[32];
    const float* fw2 = (const float*)d_in[33]; const float* fb2 = (const float*)d_in[34];

    float* bufA = (float*)d_ws;                       // NN*128 f32
    float* z    = bufA + (size_t)NN * 128;            // NG*128 f32
    float* sums = z + (size_t)NG * 128;               // 32*256 f32 (replicated)
    float* stat = sums + 32 * 256;                    // 512 f32
    unsigned char* nmg = (unsigned char*)(stat + 512);// NG*32 bytes

    hipMemsetAsync(nmg, 1, NN, stream);
    hipMemsetAsync(z, 0, (size_t)NG * 128 * sizeof(float), stream);
    setup_kernel<<<1, 128, 0, stream>>>(sums, stat, We1, ae1);

    // layer 0
    pool_gemm_kernel<41, 0, 1><<<NN / 64, 512, 0, stream>>>(
        X0, bufA, nmg, stat, g1, be1, W1, z);
    attn_kernel<<<NG, 256, 0, stream>>>(bufA, srcp, dstp, EA, nmg, stat, as1, ad1, b1, sums);
    finalize_kernel<<<1, 128, 0, stream>>>(sums, 131072.f, pw1, stat, We2, ae2);

    // layer 1 (pools layer-0 output, K=29)
    pool_gemm_kernel<128, 1, 29><<<NN / 64, 512, 0, stream>>>(
        X0, bufA, nmg, stat, g1, be1, W2, z);
    attn_kernel<<<NG, 256, 0, stream>>>(bufA, srcp, dstp, EA, nmg, stat, as2, ad2, b2, sums);
    finalize_kernel<<<1, 128, 0, stream>>>(sums, 4096.f * 29.f, pw2, stat, We3, ae3);

    // layer 2 (pools layer-1 output, K=27)
    pool_gemm_kernel<128, 2, 27><<<NN / 64, 512, 0, stream>>>(
        X0, bufA, nmg, stat, g2, be2, W3, z);
    attn_kernel<<<NG, 256, 0, stream>>>(bufA, srcp, dstp, EA, nmg, stat, as3, ad3, b3, sums);
    finalize_kernel<<<1, 128, 0, stream>>>(sums, 4096.f * 27.f, pw3, stat, We3, ae3);

    // final: pool layer-2 output (K=25) + readout + head
    final_kernel<<<NG, 256, 0, stream>>>(
        bufA, nmg, stat, g3, be3, z, fw1, fb1, fw2, fb2, (float*)d_out);
}